// Round 5
// baseline (363.633 us; speedup 1.0000x reference)
//
#include <hip/hip_runtime.h>

// incepLayer, float32 in/out. out = concat([h, f1, f2, f3]); f_k are alpha-
// mixes of P^k h, P = weighted segment_sum over edges, e = d[src]*d[dst].
//
// R4: chunked L2-resident tables (R2, proven: gather FETCH ~ compulsory)
//  +  wave-COOPERATIVE gather (fixes R2's per-lane divergent loop, the
//     measured regression: VALUBusy 20%, occ 60%, 2.2 TB/s).
// Layout: tab[c][node][8 x u64], chunk c = 32 dims = 2.56 MB < 4 MB L2;
// blocks with blockIdx%8 in {2c,2c+1} own chunk c on one XCD pair.
// Wave = 8 nodes; per node all 64 lanes cooperate: lane (q,w8) takes
// neighbor j+q, dim-word w8; scalar (s_load) loop bound -> no divergence;
// cross-q 3-step shfl_xor reduce; 512 B coalesced wave stores.

#define NN  40000
#define NE  640000
#define CAP 64   // in-degree ~ Poisson(16); P(>64) ~ 1e-17
#define NCH 4    // dim chunks (32 dims each)
#define CW  8    // u64 words per chunk-row (4 dims per u64)

typedef unsigned int uint;
typedef unsigned short ushort;
typedef unsigned long long u64;
typedef float f32x4 __attribute__((ext_vector_type(4)));

__device__ inline ushort f2h(float f) {
    _Float16 h = (_Float16)f;
    return *(ushort*)&h;
}
__device__ inline float h2f(ushort u) {
    _Float16 h = *(_Float16*)&u;
    return (float)h;
}
__device__ inline ushort f2bf(float f) {  // round-to-nearest-even
    uint x = __float_as_uint(f);
    x += 0x7fffu + ((x >> 16) & 1u);
    return (ushort)(x >> 16);
}
__device__ inline uint pack_bf2(float x, float y) {
    return ((uint)f2bf(y) << 16) | (uint)f2bf(x);
}
__device__ inline float bflo(uint u) { return __uint_as_float(u << 16); }
__device__ inline float bfhi(uint u) { return __uint_as_float(u & 0xffff0000u); }

// ---- build per-dst buckets: one uint per edge = f16(w)<<16 | src(16b) ------
__global__ __launch_bounds__(256) void build_k(
    const int* __restrict__ src, const int* __restrict__ dst,
    const float* __restrict__ deg,
    int* __restrict__ counts, uint* __restrict__ buck) {
    int e = blockIdx.x * 256 + threadIdx.x;   // NE % 256 == 0
    int s = __builtin_nontemporal_load(src + e);
    int v = __builtin_nontemporal_load(dst + e);
    int slot = atomicAdd(&counts[v], 1);
    if (slot < CAP) {
        float w = deg[s] * deg[v];
        __builtin_nontemporal_store(((uint)f2h(w) << 16) | (uint)s,
                                    &buck[v * CAP + slot]);
    }
}

// ---- convert h (f32) -> chunk-major bf16 tables, chunk->XCD affine ---------
__global__ __launch_bounds__(256) void cvt_k(
    const float* __restrict__ h, u64* __restrict__ tab) {
    int b  = blockIdx.x;
    int c  = (b & 7) >> 1;
    int wi = (b >> 3) * 2 + (b & 1);
    int t  = wi * 256 + threadIdx.x;          // u64 index within chunk
    int v  = t >> 3, w8 = t & 7;
    f32x4 hv = __builtin_nontemporal_load(
        (const f32x4*)(h + (size_t)v * 128 + c * 32 + w8 * 4));
    u64 o = ((u64)pack_bf2(hv.z, hv.w) << 32) | (u64)pack_bf2(hv.x, hv.y);
    tab[(size_t)c * NN * CW + t] = o;   // cached: resident for pass 1 gather
}

// ---- cooperative gather: wave processes 8 nodes, one at a time -------------
// lane (q,w8): neighbor-slot j+q, dim-word w8. res[4] = dims of node nbs+q.
__device__ inline void gather8(
    const u64* __restrict__ tab, const int* __restrict__ counts,
    const uint* __restrict__ buck, int nbs, int q, int w8, float res[4]) {
#pragma unroll
    for (int n = 0; n < 8; ++n) {
        int cnt = counts[nbs + n];            // scalar: s_load, uniform bound
        if (cnt > CAP) cnt = CAP;
        const uint* brow = buck + (size_t)(nbs + n) * CAP;
        float a0 = 0.f, a1 = 0.f, a2 = 0.f, a3 = 0.f;
        for (int j = 0; j < cnt; j += 8) {
            uint b = __builtin_nontemporal_load(brow + j + q);  // 32B bcast
            bool ok = (j + q) < cnt;          // tail slots hold poison
            float w = ok ? h2f((ushort)(b >> 16)) : 0.f;
            int   s = ok ? (int)(b & 0xffffu) : 0;
            u64 f = tab[(size_t)s * CW + w8]; // 64 B/row, L2-hot
            uint fl = (uint)f, fh = (uint)(f >> 32);
            a0 = fmaf(w, bflo(fl), a0); a1 = fmaf(w, bfhi(fl), a1);
            a2 = fmaf(w, bflo(fh), a2); a3 = fmaf(w, bfhi(fh), a3);
        }
#pragma unroll
        for (int m = 8; m < 64; m <<= 1) {    // reduce across q (bits 3..5)
            a0 += __shfl_xor(a0, m);
            a1 += __shfl_xor(a1, m);
            a2 += __shfl_xor(a2, m);
            a3 += __shfl_xor(a3, m);
        }
        if (q == n) { res[0] = a0; res[1] = a1; res[2] = a2; res[3] = a3; }
    }
}

// ---- aggregation pass: chunk-affine cooperative gather -> bf16 table -------
__global__ __launch_bounds__(256) void agg_k(
    const u64* __restrict__ tin, const int* __restrict__ counts,
    const uint* __restrict__ buck, u64* __restrict__ tout) {
    int b  = blockIdx.x;
    int c  = (b & 7) >> 1;
    int wi = (b >> 3) * 2 + (b & 1);
    int lane = threadIdx.x & 63, wave = threadIdx.x >> 6;
    int q = lane >> 3, w8 = lane & 7;
    int nbs = __builtin_amdgcn_readfirstlane(wi * 32 + wave * 8);
    float r[4];
    gather8(tin + (size_t)c * NN * CW, counts, buck, nbs, q, w8, r);
    u64 o = ((u64)pack_bf2(r[2], r[3]) << 32) | (u64)pack_bf2(r[0], r[1]);
    // coalesced 512 B wave store; cached: same XCD pair reads it next pass
    tout[(size_t)c * NN * CW + (size_t)(nbs + q) * CW + w8] = o;
}

// ---- final pass: gather P^3 chunk + alpha-combine + write all 4 sections ---
__global__ __launch_bounds__(256) void agg3_k(
    const u64* __restrict__ p2t, const u64* __restrict__ p1t,
    const float* __restrict__ h, const int* __restrict__ counts,
    const uint* __restrict__ buck, const float* __restrict__ alphas,
    float* __restrict__ out) {
    int b  = blockIdx.x;
    int c  = (b & 7) >> 1;
    int wi = (b >> 3) * 2 + (b & 1);
    int lane = threadIdx.x & 63, wave = threadIdx.x >> 6;
    int q = lane >> 3, w8 = lane & 7;
    int nbs = __builtin_amdgcn_readfirstlane(wi * 32 + wave * 8);
    float p3[4];
    gather8(p2t + (size_t)c * NN * CW, counts, buck, nbs, q, w8, p3);

    float a0 = alphas[0], a1 = alphas[1], a2 = alphas[2];
    float a3 = alphas[3], a4 = alphas[4], a5 = alphas[5];
    float c1p = a0, c1h = 1.f - a0;
    float c2pp = a2 * a1;
    float c2p  = a2 * (1.f - a1) + (1.f - a2) * a1;
    float c2h  = (1.f - a2) * (1.f - a1);
    float s2pp = a4 * a3;
    float s2p  = a4 * (1.f - a3) + (1.f - a4) * a3;
    float s2h  = (1.f - a4) * (1.f - a3);
    float c3ppp = a5 * s2pp;
    float c3pp  = a5 * s2p + (1.f - a5) * s2pp;
    float c3p   = a5 * s2h + (1.f - a5) * s2p;
    float c3h   = (1.f - a5) * s2h;

    int v = nbs + q;
    size_t idx = (size_t)c * NN * CW + (size_t)v * CW + w8;
    u64 u1 = p1t[idx], u2 = p2t[idx];
    float q1v[4] = { bflo((uint)u1), bfhi((uint)u1),
                     bflo((uint)(u1 >> 32)), bfhi((uint)(u1 >> 32)) };
    float q2v[4] = { bflo((uint)u2), bfhi((uint)u2),
                     bflo((uint)(u2 >> 32)), bfhi((uint)(u2 >> 32)) };
    f32x4 hv = __builtin_nontemporal_load(
        (const f32x4*)(h + (size_t)v * 128 + c * 32 + w8 * 4));
    float hf[4] = { hv.x, hv.y, hv.z, hv.w };

    f32x4 r1, r2, r3;
#pragma unroll
    for (int k = 0; k < 4; ++k) {
        r1[k] = c1p * q1v[k] + c1h * hf[k];
        r2[k] = c2pp * q2v[k] + c2p * q1v[k] + c2h * hf[k];
        r3[k] = c3ppp * p3[k] + c3pp * q2v[k] + c3p * q1v[k] + c3h * hf[k];
    }

    float* o = out + (size_t)v * 512 + c * 32 + w8 * 4;
    __builtin_nontemporal_store(hv, (f32x4*)(o));
    __builtin_nontemporal_store(r1, (f32x4*)(o + 128));
    __builtin_nontemporal_store(r2, (f32x4*)(o + 256));
    __builtin_nontemporal_store(r3, (f32x4*)(o + 384));
}

extern "C" void kernel_launch(void* const* d_in, const int* in_sizes, int n_in,
                              void* d_out, int out_size, void* d_ws, size_t ws_size,
                              hipStream_t stream) {
    const float* h      = (const float*)d_in[0];
    const float* deg    = (const float*)d_in[1];
    const float* alphas = (const float*)d_in[2];
    const int*   src    = (const int*)d_in[3];
    const int*   dst    = (const int*)d_in[4];
    float* out = (float*)d_out;

    // ws layout (bytes): counts 160,000 | buck 10,240,000 |
    //                    hb 10,240,000 | p1b 10,240,000 | p2b 10,240,000
    char* ws = (char*)d_ws;
    int*  counts = (int*)(ws + 0);
    uint* buck   = (uint*)(ws + 160000);
    u64*  hb     = (u64*)(ws + 10400000);
    u64*  p1b    = (u64*)(ws + 20640000);
    u64*  p2b    = (u64*)(ws + 30880000);

    hipMemsetAsync(counts, 0, NN * sizeof(int), stream);
    build_k<<<NE / 256, 256, 0, stream>>>(src, dst, deg, counts, buck);
    cvt_k<<<NN * NCH * CW / 256, 256, 0, stream>>>(h, hb);     // 5000 blocks

    agg_k<<<NN * NCH / 32, 256, 0, stream>>>(hb,  counts, buck, p1b);  // 5000
    agg_k<<<NN * NCH / 32, 256, 0, stream>>>(p1b, counts, buck, p2b);  // 5000
    agg3_k<<<NN * NCH / 32, 256, 0, stream>>>(p2b, p1b, h, counts, buck,
                                              alphas, out);            // 5000
}

// Round 6
// 226.541 us; speedup vs baseline: 1.6052x; 1.6052x over previous
//
#include <hip/hip_runtime.h>

// incepLayer, float32 in/out. out = concat([h, f1, f2, f3]); f_k are alpha-
// mixes of P^k h, P = weighted segment_sum over edges, e = d[src]*d[dst].
//
// R5: revert chunking (R2/R4 regressed: bucket traffic xNCH + NT-latency on
// the dependent chain; table was already L3-resident). Back to R1 structure
// (wave per node, bf16 rows, 10.24 MB table) with ONE change: gather loads
// are dwordx4 (16 B/lane). 16 lanes cover one 256 B row -> one instruction
// fetches FOUR edges' rows (1 KB). 4x fewer vmem instructions, 4x bytes in
// flight per queue entry -> latency-bound gather gets 4x concurrency.
// Lane (g,t), g=lane>>4 edge-subgroup, t=lane&15 dim-16th: acc 8 dims f32;
// 2-step shfl_xor butterfly (16,32) merges subgroups once per node.
// Numerics identical to verified rounds: f16 weights, bf16 rows, f32 acc.

#define NN  40000
#define NE  640000
#define CAP 64   // in-degree ~ Poisson(16); P(>64) ~ 1e-17

typedef unsigned int uint;
typedef unsigned short ushort;
typedef float f32x4 __attribute__((ext_vector_type(4)));
typedef uint  u32x4 __attribute__((ext_vector_type(4)));

__device__ inline ushort f2h(float f) {
    _Float16 h = (_Float16)f;
    return *(ushort*)&h;
}
__device__ inline float h2f(ushort u) {
    _Float16 h = *(_Float16*)&u;
    return (float)h;
}
__device__ inline ushort f2bf(float f) {  // round-to-nearest-even
    uint x = __float_as_uint(f);
    x += 0x7fffu + ((x >> 16) & 1u);
    return (ushort)(x >> 16);
}
__device__ inline uint pack_bf2(float x, float y) {
    return ((uint)f2bf(y) << 16) | (uint)f2bf(x);
}
__device__ inline float bflo(uint u) { return __uint_as_float(u << 16); }
__device__ inline float bfhi(uint u) { return __uint_as_float(u & 0xffff0000u); }

// ---- build per-dst buckets: one uint per edge = f16(w)<<16 | src(16b) ------
__global__ __launch_bounds__(256) void build_k(
    const int* __restrict__ src, const int* __restrict__ dst,
    const float* __restrict__ deg,
    int* __restrict__ counts, uint* __restrict__ buck) {
    int e = blockIdx.x * 256 + threadIdx.x;   // NE % 256 == 0
    int s = __builtin_nontemporal_load(src + e);
    int v = __builtin_nontemporal_load(dst + e);
    int slot = atomicAdd(&counts[v], 1);
    if (slot < CAP) {
        float w = deg[s] * deg[v];
        buck[v * CAP + slot] = ((uint)f2h(w) << 16) | (uint)s;  // cached store
    }
}

// ---- convert h (f32) -> hb (bf16 rows, 64 uints per row) -------------------
__global__ __launch_bounds__(256) void cvt_k(
    const float* __restrict__ h, uint* __restrict__ hb) {
    int i = blockIdx.x * 256 + threadIdx.x;   // one uint (2 dims) per thread
    float2 f = *(const float2*)(h + (size_t)i * 2);
    hb[i] = pack_bf2(f.x, f.y);
}

// ---- gather: wave per node; lane (g,t) = edge j+g, dims [8t..8t+8) ---------
__device__ inline void gather16(
    const uint* __restrict__ feat, const int* __restrict__ counts,
    const uint* __restrict__ buck, int v, int lane, float acc[8]) {
    int vs = __builtin_amdgcn_readfirstlane(v);
    int cnt = counts[vs];
    if (cnt > CAP) cnt = CAP;
    uint myw = buck[(size_t)vs * CAP + lane];   // 256B coalesced, lane j = slot j
    int g = lane >> 4, t = lane & 15;
#pragma unroll
    for (int k = 0; k < 8; ++k) acc[k] = 0.f;
#pragma unroll 2
    for (int j = 0; j < cnt; j += 4) {
        uint u = __shfl(myw, j + g);            // slot for my subgroup
        bool ok = (j + g) < cnt;                // tail slots hold poison
        float w = ok ? h2f((ushort)(u >> 16)) : 0.f;
        int   s = ok ? (int)(u & 0xffffu) : 0;  // mask: poison idx could OOB ws
        u32x4 f = *(const u32x4*)(feat + (size_t)s * 64 + t * 4);  // 16B/lane
        acc[0] = fmaf(w, bflo(f.x), acc[0]); acc[1] = fmaf(w, bfhi(f.x), acc[1]);
        acc[2] = fmaf(w, bflo(f.y), acc[2]); acc[3] = fmaf(w, bfhi(f.y), acc[3]);
        acc[4] = fmaf(w, bflo(f.z), acc[4]); acc[5] = fmaf(w, bfhi(f.z), acc[5]);
        acc[6] = fmaf(w, bflo(f.w), acc[6]); acc[7] = fmaf(w, bfhi(f.w), acc[7]);
    }
#pragma unroll
    for (int k = 0; k < 8; ++k) {               // merge 4 edge-subgroups
        acc[k] += __shfl_xor(acc[k], 16);
        acc[k] += __shfl_xor(acc[k], 32);
    }
}

// ---- aggregation pass: gather bf16 rows -> write bf16 rows -----------------
__global__ __launch_bounds__(256) void agg_k(
    const uint* __restrict__ feat,
    const int* __restrict__ counts, const uint* __restrict__ buck,
    uint* __restrict__ outf) {
    int gid  = blockIdx.x * 256 + threadIdx.x;
    int v    = gid >> 6;
    int lane = gid & 63;
    if (v >= NN) return;
    float acc[8];
    gather16(feat, counts, buck, v, lane, acc);
    if (lane < 16) {                            // 16 lanes x 16B = 256B row
        u32x4 o;
        o.x = pack_bf2(acc[0], acc[1]); o.y = pack_bf2(acc[2], acc[3]);
        o.z = pack_bf2(acc[4], acc[5]); o.w = pack_bf2(acc[6], acc[7]);
        *(u32x4*)(outf + (size_t)v * 64 + lane * 4) = o;
    }
}

// ---- final pass: gather P^3; subgroup g emits output section g -------------
__global__ __launch_bounds__(256) void agg3_k(
    const uint* __restrict__ p2b, const uint* __restrict__ p1b,
    const float* __restrict__ h, const int* __restrict__ counts,
    const uint* __restrict__ buck, const float* __restrict__ alphas,
    float* __restrict__ out) {
    int gid  = blockIdx.x * 256 + threadIdx.x;
    int v    = gid >> 6;
    int lane = gid & 63;
    if (v >= NN) return;
    float p3[8];
    gather16(p2b, counts, buck, v, lane, p3);

    float a0 = alphas[0], a1 = alphas[1], a2 = alphas[2];
    float a3 = alphas[3], a4 = alphas[4], a5 = alphas[5];
    float s2pp = a4 * a3;
    float s2p  = a4 * (1.f - a3) + (1.f - a4) * a3;
    float s2h  = (1.f - a4) * (1.f - a3);
    // per-section coefficient 4-vectors (cp3, cq2, cq1, ch), section = g
    int g = lane >> 4, t = lane & 15;
    float cp3 = (g == 3) ? a5 * s2pp : 0.f;
    float cq2 = (g == 3) ? a5 * s2p + (1.f - a5) * s2pp
              : (g == 2) ? a2 * a1 : 0.f;
    float cq1 = (g == 3) ? a5 * s2h + (1.f - a5) * s2p
              : (g == 2) ? a2 * (1.f - a1) + (1.f - a2) * a1
              : (g == 1) ? a0 : 0.f;
    float ch  = (g == 3) ? (1.f - a5) * s2h
              : (g == 2) ? (1.f - a2) * (1.f - a1)
              : (g == 1) ? 1.f - a0 : 1.f;

    u32x4 u1 = *(const u32x4*)(p1b + (size_t)v * 64 + t * 4);
    u32x4 u2 = *(const u32x4*)(p2b + (size_t)v * 64 + t * 4);
    f32x4 h0 = *(const f32x4*)(h + (size_t)v * 128 + t * 8);
    f32x4 h1 = *(const f32x4*)(h + (size_t)v * 128 + t * 8 + 4);
    float q1[8] = { bflo(u1.x), bfhi(u1.x), bflo(u1.y), bfhi(u1.y),
                    bflo(u1.z), bfhi(u1.z), bflo(u1.w), bfhi(u1.w) };
    float q2[8] = { bflo(u2.x), bfhi(u2.x), bflo(u2.y), bfhi(u2.y),
                    bflo(u2.z), bfhi(u2.z), bflo(u2.w), bfhi(u2.w) };
    float hf[8] = { h0.x, h0.y, h0.z, h0.w, h1.x, h1.y, h1.z, h1.w };

    f32x4 r0, r1;
#pragma unroll
    for (int k = 0; k < 4; ++k)
        r0[k] = cp3 * p3[k] + cq2 * q2[k] + cq1 * q1[k] + ch * hf[k];
#pragma unroll
    for (int k = 0; k < 4; ++k)
        r1[k] = cp3 * p3[k+4] + cq2 * q2[k+4] + cq1 * q1[k+4] + ch * hf[k+4];
    if (g == 0) {   // section 0 must be bit-exact h passthrough
        r0 = h0; r1 = h1;
    }

    float* o = out + (size_t)v * 512 + g * 128 + t * 8;   // section g
    __builtin_nontemporal_store(r0, (f32x4*)(o));
    __builtin_nontemporal_store(r1, (f32x4*)(o + 4));
}

extern "C" void kernel_launch(void* const* d_in, const int* in_sizes, int n_in,
                              void* d_out, int out_size, void* d_ws, size_t ws_size,
                              hipStream_t stream) {
    const float* h      = (const float*)d_in[0];
    const float* deg    = (const float*)d_in[1];
    const float* alphas = (const float*)d_in[2];
    const int*   src    = (const int*)d_in[3];
    const int*   dst    = (const int*)d_in[4];
    float* out = (float*)d_out;

    // ws layout (bytes): counts 160,000 | buck 10,240,000 |
    //                    hb 10,240,000 | p1b 10,240,000 | p2b 10,240,000
    char* ws = (char*)d_ws;
    int*  counts = (int*)(ws + 0);
    uint* buck   = (uint*)(ws + 160000);
    uint* hb     = (uint*)(ws + 10400000);
    uint* p1b    = (uint*)(ws + 20640000);
    uint* p2b    = (uint*)(ws + 30880000);

    hipMemsetAsync(counts, 0, NN * sizeof(int), stream);
    build_k<<<NE / 256, 256, 0, stream>>>(src, dst, deg, counts, buck);
    cvt_k<<<NN * 64 / 256, 256, 0, stream>>>(h, hb);               // 10000

    agg_k<<<NN * 64 / 256, 256, 0, stream>>>(hb,  counts, buck, p1b);
    agg_k<<<NN * 64 / 256, 256, 0, stream>>>(p1b, counts, buck, p2b);
    agg3_k<<<NN * 64 / 256, 256, 0, stream>>>(p2b, p1b, h, counts, buck,
                                              alphas, out);
}